// Round 2
// baseline (6733.585 us; speedup 1.0000x reference)
//
#include <hip/hip_runtime.h>
#include <hip/hip_bf16.h>

#define TOT85 1722695ULL  // 85 * 20267

using short8 = __attribute__((ext_vector_type(8))) short;
using f32x4  = __attribute__((ext_vector_type(4))) float;

__device__ __forceinline__ float bfbits2f(short u) {
  return __uint_as_float(((unsigned int)(unsigned short)u) << 16);
}
__device__ __forceinline__ short f2bfbits(float f) {
  __hip_bfloat16 h = __float2bfloat16(f);
  return *reinterpret_cast<short*>(&h);
}

__device__ __forceinline__ void gload_lds16(const void* g, void* l) {
  __builtin_amdgcn_global_load_lds(
      (const __attribute__((address_space(1))) unsigned int*)g,
      (__attribute__((address_space(3))) unsigned int*)l, 16, 0, 0);
}

// repack conv weight [O][256][3][3] f32 -> [step 72 = chunk*9+tap][NOCP oc][40 (32ic+pad8)] bf16
// step-major so the kernel streams steps contiguously; pad-40 rows make LDS reads 2-way-free.
__global__ __launch_bounds__(256) void repack_k(const float* __restrict__ src,
                                                __hip_bfloat16* __restrict__ dst,
                                                int O, int NOCP, int ocoff) {
  int idx = blockIdx.x * 256 + threadIdx.x;
  if (idx >= O * 2304) return;
  int o = idx / 2304;
  int r = idx - o * 2304;
  int i = r / 9;       // ic 0..255
  int t = r - i * 9;   // tap 0..8
  dst[((size_t)((i >> 5) * 9 + t) * NOCP + (o + ocoff)) * 40 + (i & 31)] =
      __float2bfloat16(src[idx]);
}

__global__ void locations_k(float* __restrict__ out, int HW, int W, float s) {
  int i = blockIdx.x * 256 + threadIdx.x;
  if (i >= HW) return;
  int y = i / W, x = i - y * W;
  out[2 * i + 0] = x * s + 0.5f * s;
  out[2 * i + 1] = y * s + 0.5f * s;
}

// Implicit-GEMM conv3x3 via MFMA 16x16x32 bf16.
// Block: 256 thr = 4 waves (2M x 2N). Tile: 128 pixels (8 rows x 16 cols) x NOC ocs.
// K-loop: 8 ic-chunks x 9 taps, K=32 per step.
// s_in: [10][18][40] bf16. NREP==8: weights stream global->LDS via global_load_lds,
// 3 buffers, 2-tap-deep pipeline, raw s_barrier + counted vmcnt (never 0 in loop).
// Input for next chunk prefetched to regs at tap 7 (issue-early/write-late).
// Heads (NREP 3/1) keep the register double-buffer weight path.
// GN finalize fused: NORM_IN blocks compute per-channel a/c from statsIn.
// OUT_MODE: 0 = NHWC bf16 dst; 1 = d_out fp32 (logits oc<80, ctr oc==80 -> ch84);
//           2 = d_out fp32 expf(scale*v) at ch 80+oc.
template <int NREP, bool NORM_IN, bool STATS, int OUT_MODE, bool SRC_NCHW>
__global__ __launch_bounds__(256, 2) void conv_mfma_k(
    const void* __restrict__ srcv, const __hip_bfloat16* __restrict__ wpk,
    const float* __restrict__ bias, const float* __restrict__ bias2,
    const float* __restrict__ statsIn, const float* __restrict__ gamma,
    const float* __restrict__ beta, float inv_cnt,
    __hip_bfloat16* __restrict__ dst, float* __restrict__ out,
    float* __restrict__ statsOut, const float* __restrict__ scales, int lvl,
    int H, int W, int oc_valid, int nTx) {
  constexpr int NOC = NREP * 32;
  constexpr bool WLDS = (NREP == 8);
  constexpr int WSTEP = NOC * 40;  // shorts per step
  __shared__ __align__(16) short s_in[180 * 40];
  __shared__ __align__(16) short s_w[WLDS ? 3 * 256 * 40 : 8];
  __shared__ float s_red[64];
  __shared__ float s_a[256], s_c[256];

  const int tid = threadIdx.x;
  const int lane = tid & 63;
  const int wave = tid >> 6;
  const int wm = wave >> 1;  // 0..1
  const int wn = wave & 1;   // 0..1
  const int tIdx = blockIdx.x;
  const int ty = tIdx / nTx, tx = tIdx - ty * nTx;
  const int x0 = tx * 16, y0 = ty * 8;
  const int b = blockIdx.z;
  const int HW = H * W;
  const int l15 = lane & 15;
  const int kg = lane >> 4;  // 0..3
  const int q8 = (tid & 3) * 8;

  if (STATS && tid < 64) s_red[tid] = 0.f;
  if (NORM_IN) {
    int g = tid >> 3;
    float s = statsIn[(b * 32 + g) * 2 + 0];
    float ss = statsIn[(b * 32 + g) * 2 + 1];
    float m = s * inv_cnt;
    float var = fmaf(-m, m, ss * inv_cnt);
    float rs = rsqrtf(var + 1e-5f);
    float avv = rs * gamma[tid];
    s_a[tid] = avv;
    s_c[tid] = fmaf(-m, avv, beta[tid]);
  }

  f32x4 acc[4][NREP];
#pragma unroll
  for (int m = 0; m < 4; ++m)
#pragma unroll
    for (int n = 0; n < NREP; ++n) acc[m][n] = (f32x4){0.f, 0.f, 0.f, 0.f};

  if constexpr (WLDS) {
    // ---- weight glds issue: 5 x 16B per thread = one 20480B step ----
    auto wissue = [&](int Tn) {
      int Tw = (Tn >= 72) ? Tn - 72 : Tn;  // wrap: harmless dead loads at the end
      const short* src = (const short*)wpk + (size_t)Tw * WSTEP + wave * 512 + lane * 8;
      short* dstb = s_w + (Tw % 3) * WSTEP + wave * 512;  // uniform per wave (lane*16B implicit)
#pragma unroll
      for (int r = 0; r < 5; ++r) gload_lds16(src + r * 2048, dstb + r * 2048);
    };

    short8 pv[3];
    for (int c = 0; c < 8; ++c) {
      if (c == 0) { wissue(0); wissue(1); }
      asm volatile("s_waitcnt lgkmcnt(0)" ::: "memory");  // prev readers done before s_in rewrite
      __builtin_amdgcn_s_barrier();
      // ---- stage s_in for chunk c ----
      if constexpr (SRC_NCHW) {
        const float* srcf = (const float*)srcv;
        const int pix = tid;
        if (pix < 180) {
          int prow = pix / 18;
          int pcol = pix - prow * 18;
          int gy = y0 + prow - 1, gx = x0 + pcol - 1;
          short8 sv[4];
          bool valid = (gy >= 0 && gy < H && gx >= 0 && gx < W);
          if (valid) {
            const float* p = srcf + (((size_t)(b * 256 + c * 32)) * H + gy) * W + gx;
#pragma unroll
            for (int qq = 0; qq < 4; ++qq)
#pragma unroll
              for (int j = 0; j < 8; ++j)
                sv[qq][j] = f2bfbits(p[(size_t)(qq * 8 + j) * HW]);
          } else {
#pragma unroll
            for (int qq = 0; qq < 4; ++qq) sv[qq] = (short8)0;
          }
#pragma unroll
          for (int qq = 0; qq < 4; ++qq) *(short8*)(s_in + pix * 40 + qq * 8) = sv[qq];
        }
      } else {
        const __hip_bfloat16* srcb = (const __hip_bfloat16*)srcv;
        float av[8], cv[8];
#pragma unroll
        for (int j = 0; j < 8; ++j) {
          int c2 = c * 32 + q8 + j;
          av[j] = s_a[c2];
          cv[j] = s_c[c2];
        }
#pragma unroll
        for (int r = 0; r < 3; ++r) {
          int idx = r * 256 + tid;
          int pix = idx >> 2;
          int prow = pix / 18;
          int pcol = pix - prow * 18;
          int gy = y0 + prow - 1, gx = x0 + pcol - 1;
          bool valid = (gy >= 0 && gy < H && gx >= 0 && gx < W);
          short8 v8;
          if (c == 0) {
            v8 = (short8)0;
            if (valid)
              v8 = *(const short8*)((const short*)srcb +
                                    ((((size_t)b * H + gy) * W + gx) * 256 + q8));
          } else {
            v8 = pv[r];
          }
          short8 o8 = (short8)0;
          if (valid) {
#pragma unroll
            for (int j = 0; j < 8; ++j)
              o8[j] = f2bfbits(fmaxf(fmaf(bfbits2f(v8[j]), av[j], cv[j]), 0.f));
          }
          *(short8*)(s_in + pix * 40 + q8) = o8;
        }
      }
      // first tap's weight buffer ready; keep the next one in flight
      asm volatile("s_waitcnt vmcnt(5) lgkmcnt(0)" ::: "memory");
      __builtin_amdgcn_s_barrier();
      // ---- taps ----
#pragma unroll
      for (int tap = 0; tap < 9; ++tap) {
        wissue(c * 9 + tap + 2);
        if constexpr (!SRC_NCHW) {
          if (tap == 7) {  // prefetch next chunk's input (always; last chunk wraps, unused)
            int nc = (c + 1) & 7;
            const __hip_bfloat16* srcb = (const __hip_bfloat16*)srcv;
#pragma unroll
            for (int r = 0; r < 3; ++r) {
              int idx = r * 256 + tid;
              int pix = idx >> 2;
              int prow = pix / 18;
              int pcol = pix - prow * 18;
              int gy = y0 + prow - 1, gx = x0 + pcol - 1;
              pv[r] = (short8)0;
              if (gy >= 0 && gy < H && gx >= 0 && gx < W)
                pv[r] = *(const short8*)((const short*)srcb +
                                         ((((size_t)b * H + gy) * W + gx) * 256 + nc * 32 + q8));
            }
          }
        }
        const int dy = tap / 3, dx = tap - dy * 3;
        const short* wbuf = s_w + (tap % 3) * WSTEP;  // (c*9+tap)%3 == tap%3
        short8 af[4];
#pragma unroll
        for (int m = 0; m < 4; ++m)
          af[m] = *(const short8*)(s_in + ((wm * 4 + m + dy) * 18 + (l15 + dx)) * 40 + kg * 8);
        short8 wf[8];
#pragma unroll
        for (int n = 0; n < 8; ++n)
          wf[n] = *(const short8*)(wbuf + (wn * 128 + n * 16 + l15) * 40 + kg * 8);
#pragma unroll
        for (int m = 0; m < 4; ++m)
#pragma unroll
          for (int n = 0; n < 8; ++n)
            acc[m][n] = __builtin_amdgcn_mfma_f32_16x16x32_bf16(af[m], wf[n], acc[m][n], 0, 0, 0);
        if (tap < 8) {
          if (tap == 7 && !SRC_NCHW)
            asm volatile("s_waitcnt vmcnt(8) lgkmcnt(0)" ::: "memory");  // +3 input prefetch
          else
            asm volatile("s_waitcnt vmcnt(5) lgkmcnt(0)" ::: "memory");
          __builtin_amdgcn_s_barrier();
        }
      }
    }
    // drain stray glds/prefetch before epilogue (LDS gets reallocated after endpgm)
    asm volatile("s_waitcnt vmcnt(0)" ::: "memory");
  } else {
    // ---- heads: register-double-buffered weights from global (step-major, stride-40) ----
    const short* wlane = (const short*)wpk + ((wn * NREP * 16 + l15) * 40 + kg * 8);
    for (int c = 0; c < 8; ++c) {
      const int ic0 = c * 32;
      __syncthreads();
      {
        const __hip_bfloat16* srcb = (const __hip_bfloat16*)srcv;
        float av[8], cv[8];
#pragma unroll
        for (int j = 0; j < 8; ++j) {
          int c2 = ic0 + q8 + j;
          av[j] = s_a[c2];
          cv[j] = s_c[c2];
        }
        for (int idx = tid; idx < 720; idx += 256) {
          int pix = idx >> 2;
          int prow = pix / 18;
          int pcol = pix - prow * 18;
          int gy = y0 + prow - 1, gx = x0 + pcol - 1;
          short8 o8 = (short8)0;
          if (gy >= 0 && gy < H && gx >= 0 && gx < W) {
            const short* sp =
                (const short*)srcb + ((((size_t)b * H + gy) * W + gx) * 256 + ic0 + q8);
            short8 v8 = *(const short8*)sp;
#pragma unroll
            for (int j = 0; j < 8; ++j)
              o8[j] = f2bfbits(fmaxf(fmaf(bfbits2f(v8[j]), av[j], cv[j]), 0.f));
          }
          *(short8*)(s_in + pix * 40 + q8) = o8;
        }
      }
      __syncthreads();

      const short* wch = wlane + (size_t)(c * 9) * WSTEP;
      short8 bwA[NREP], bwB[NREP];
#pragma unroll
      for (int n = 0; n < NREP; ++n) bwA[n] = *(const short8*)(wch + n * 640);

      auto tapbody = [&](int tap, short8* curw, short8* nxtw) {
        if (tap < 8) {
          const short* wt = wch + (size_t)(tap + 1) * WSTEP;
#pragma unroll
          for (int n = 0; n < NREP; ++n) nxtw[n] = *(const short8*)(wt + n * 640);
        }
        const int dy = tap / 3, dx = tap - dy * 3;
        short8 af[4];
#pragma unroll
        for (int m = 0; m < 4; ++m)
          af[m] = *(const short8*)(s_in + ((wm * 4 + m + dy) * 18 + (l15 + dx)) * 40 + kg * 8);
#pragma unroll
        for (int m = 0; m < 4; ++m)
#pragma unroll
          for (int n = 0; n < NREP; ++n)
            acc[m][n] = __builtin_amdgcn_mfma_f32_16x16x32_bf16(af[m], curw[n], acc[m][n], 0, 0, 0);
      };
#pragma unroll
      for (int tap = 0; tap < 9; tap += 2) {
        tapbody(tap, bwA, bwB);
        if (tap + 1 < 9) tapbody(tap + 1, bwB, bwA);
      }
    }
  }

  // epilogue: bias, store, GN stats
  const int masks[5] = {1, 2, 4, 16, 32};
#pragma unroll
  for (int n = 0; n < NREP; ++n) {
    int oc_l = wn * NREP * 16 + n * 16 + l15;
    float bv;
    if (OUT_MODE == 1)
      bv = (oc_l < 80) ? bias[oc_l] : ((oc_l == 80) ? bias2[0] : 0.f);
    else
      bv = (oc_l < oc_valid) ? bias[oc_l] : 0.f;
    float lsum = 0.f, lssq = 0.f;
#pragma unroll
    for (int m = 0; m < 4; ++m) {
      int oy = y0 + wm * 4 + m;
#pragma unroll
      for (int r = 0; r < 4; ++r) {
        int ox = x0 + kg * 4 + r;
        bool valid = (oy < H) && (ox < W) && (oc_l < oc_valid);
        float v = acc[m][n][r] + bv;
        if (valid) {
          if (OUT_MODE == 0) {
            dst[(((size_t)b * H + oy) * W + ox) * 256 + oc_l] = __float2bfloat16(v);
          } else if (OUT_MODE == 1) {
            int och = (oc_l == 80) ? 84 : oc_l;
            out[(size_t)b * TOT85 + (size_t)och * HW + oy * W + ox] = v;
          } else {
            out[(size_t)b * TOT85 + (size_t)(80 + oc_l) * HW + oy * W + ox] =
                expf(scales[lvl] * v);
          }
          if (STATS) {
            lsum += v;
            lssq += v * v;
          }
        }
      }
    }
    if (STATS) {
#pragma unroll
      for (int s = 0; s < 5; ++s) {
        lsum += __shfl_xor(lsum, masks[s], 64);
        lssq += __shfl_xor(lssq, masks[s], 64);
      }
      if ((lane & 55) == 0) {  // lanes 0 and 8
        int g2 = ((wn * NREP + n) * 2 + ((lane >> 3) & 1)) * 2;
        atomicAdd(&s_red[g2 + 0], lsum);
        atomicAdd(&s_red[g2 + 1], lssq);
      }
    }
  }
  if (STATS) {
    __syncthreads();
    if (tid < 64) atomicAdd(&statsOut[(size_t)b * 64 + tid], s_red[tid]);
  }
}

extern "C" void kernel_launch(void* const* d_in, const int* in_sizes, int n_in,
                              void* d_out_v, int out_size, void* d_ws, size_t ws_size,
                              hipStream_t stream) {
  (void)in_sizes; (void)n_in; (void)out_size; (void)ws_size;
  static const int HS[5] = {100, 50, 25, 13, 7};
  static const int WSd[5] = {152, 76, 38, 19, 10};
  static const int STRD[5] = {8, 16, 32, 64, 128};

  const float* feat[5];
  for (int i = 0; i < 5; ++i) feat[i] = (const float*)d_in[i];
  const float* cls_w = (const float*)d_in[5];
  const float* cls_b = (const float*)d_in[6];
  const float* cls_g = (const float*)d_in[7];
  const float* cls_bb = (const float*)d_in[8];
  const float* box_w = (const float*)d_in[9];
  const float* box_b = (const float*)d_in[10];
  const float* box_g = (const float*)d_in[11];
  const float* box_bb = (const float*)d_in[12];
  const float* logits_w = (const float*)d_in[13];
  const float* logits_b = (const float*)d_in[14];
  const float* ctr_w = (const float*)d_in[15];
  const float* ctr_b = (const float*)d_in[16];
  const float* reg_w = (const float*)d_in[17];
  const float* reg_b = (const float*)d_in[18];
  const float* scales = (const float*)d_in[19];
  float* d_out = (float*)d_out_v;

  char* wsp = (char*)d_ws;
  size_t off = 0;
  auto carve = [&](size_t bytes) -> char* {
    char* p = wsp + off;
    off += (bytes + 255) & ~(size_t)255;
    return p;
  };
  const size_t MAXE = (size_t)8 * 100 * 152 * 256;  // 31.13M elems
  __hip_bfloat16* bufA = (__hip_bfloat16*)carve(MAXE * 2);
  __hip_bfloat16* bufB = (__hip_bfloat16*)carve(MAXE * 2);
  const size_t TW = (size_t)72 * 256 * 40;  // padded step-major, per tower conv
  __hip_bfloat16* wpk_cls = (__hip_bfloat16*)carve(4 * TW * 2);
  __hip_bfloat16* wpk_box = (__hip_bfloat16*)carve(4 * TW * 2);
  __hip_bfloat16* wpk_clsh = (__hip_bfloat16*)carve((size_t)72 * 96 * 40 * 2);
  __hip_bfloat16* wpk_regh = (__hip_bfloat16*)carve((size_t)72 * 32 * 40 * 2);
  float* stats_all = (float*)carve((size_t)40 * 8 * 64 * 4);

  hipMemsetAsync(stats_all, 0, (size_t)40 * 8 * 64 * 4, stream);

  auto rp = [&](const float* s, __hip_bfloat16* d, int O, int NOCP, int ocoff) {
    int total = O * 2304;
    hipLaunchKernelGGL(repack_k, dim3((total + 255) / 256), dim3(256), 0, stream, s, d, O, NOCP,
                       ocoff);
  };
  for (int i = 0; i < 4; ++i) {
    rp(cls_w + (size_t)i * 256 * 2304, wpk_cls + (size_t)i * TW, 256, 256, 0);
    rp(box_w + (size_t)i * 256 * 2304, wpk_box + (size_t)i * TW, 256, 256, 0);
  }
  rp(logits_w, wpk_clsh, 80, 96, 0);
  rp(ctr_w, wpk_clsh, 1, 96, 80);
  rp(reg_w, wpk_regh, 4, 32, 0);

  size_t out_lvl_off = 0, loc_off = 0;
  const size_t OUT0 = (size_t)8 * TOT85;

  for (int l = 0; l < 5; ++l) {
    int H = HS[l], W = WSd[l], HW = H * W;
    int nTx = (W + 15) / 16, nTy = (H + 7) / 8;
    dim3 grid(nTx * nTy, 1, 8);
    dim3 blk(256);
    float inv_cnt = 1.f / (8.f * (float)HW);
    float* out_lvl = d_out + out_lvl_off;

    hipLaunchKernelGGL(locations_k, dim3((HW + 255) / 256), blk, 0, stream,
                       d_out + OUT0 + 2 * loc_off, HW, W, (float)STRD[l]);

    for (int t = 0; t < 2; ++t) {
      const __hip_bfloat16* wpkT = (t == 0) ? wpk_cls : wpk_box;
      const float* bt = (t == 0) ? cls_b : box_b;
      const float* gt = (t == 0) ? cls_g : box_g;
      const float* bbt = (t == 0) ? cls_bb : box_bb;
      float* slot = stats_all + (size_t)(l * 2 + t) * 4 * 512;  // 512 floats per conv slot

      // conv 0: NCHW f32 input, no norm, writes stats slot 0
      hipLaunchKernelGGL((conv_mfma_k<8, false, true, 0, true>), grid, blk, 0, stream,
                         (const void*)feat[l], wpkT, bt, (const float*)nullptr,
                         (const float*)nullptr, (const float*)nullptr, (const float*)nullptr,
                         0.f, bufA, (float*)nullptr, slot, scales, l, H, W, 256, nTx);
      __hip_bfloat16* cur = bufA;
      __hip_bfloat16* nxt = bufB;
      for (int i = 1; i < 4; ++i) {
        hipLaunchKernelGGL((conv_mfma_k<8, true, true, 0, false>), grid, blk, 0, stream,
                           (const void*)cur, wpkT + (size_t)i * TW, bt + i * 256,
                           (const float*)nullptr, slot + (size_t)(i - 1) * 512,
                           gt + (i - 1) * 256, bbt + (i - 1) * 256, inv_cnt, nxt,
                           (float*)nullptr, slot + (size_t)i * 512, scales, l, H, W, 256, nTx);
        __hip_bfloat16* tmp = cur;
        cur = nxt;
        nxt = tmp;
      }
      if (t == 0) {
        hipLaunchKernelGGL((conv_mfma_k<3, true, false, 1, false>), grid, blk, 0, stream,
                           (const void*)cur, wpk_clsh, logits_b, ctr_b,
                           slot + (size_t)3 * 512, gt + 3 * 256, bbt + 3 * 256, inv_cnt,
                           (__hip_bfloat16*)nullptr, out_lvl, (float*)nullptr, scales, l, H, W,
                           81, nTx);
      } else {
        hipLaunchKernelGGL((conv_mfma_k<1, true, false, 2, false>), grid, blk, 0, stream,
                           (const void*)cur, wpk_regh, reg_b, (const float*)nullptr,
                           slot + (size_t)3 * 512, gt + 3 * 256, bbt + 3 * 256, inv_cnt,
                           (__hip_bfloat16*)nullptr, out_lvl, (float*)nullptr, scales, l, H, W,
                           4, nTx);
      }
    }
    out_lvl_off += (size_t)85 * HW;
    loc_off += HW;
  }
}

// Round 3
// 4975.422 us; speedup vs baseline: 1.3534x; 1.3534x over previous
//
#include <hip/hip_runtime.h>
#include <hip/hip_bf16.h>

#define TOT85 1722695ULL  // 85 * 20267

using short8 = __attribute__((ext_vector_type(8))) short;
using f32x4  = __attribute__((ext_vector_type(4))) float;

__device__ __forceinline__ float bfbits2f(short u) {
  return __uint_as_float(((unsigned int)(unsigned short)u) << 16);
}
__device__ __forceinline__ short f2bfbits(float f) {
  __hip_bfloat16 h = __float2bfloat16(f);
  return *reinterpret_cast<short*>(&h);
}

// repack conv weight [O][256][3][3] f32 -> [tap 9][chunk 8][NOCP oc][32 ic] bf16
// (no pad: weights are consumed straight from global/L2; stride-32 rows make each
// 16-oc x 8-ic fragment load a contiguous, fully-coalesced 1KB wave transaction)
__global__ __launch_bounds__(256) void repack_k(const float* __restrict__ src,
                                                __hip_bfloat16* __restrict__ dst,
                                                int O, int NOCP, int ocoff) {
  int idx = blockIdx.x * 256 + threadIdx.x;
  if (idx >= O * 2304) return;
  int o = idx / 2304;
  int r = idx - o * 2304;
  int i = r / 9;       // ic 0..255
  int t = r - i * 9;   // tap 0..8
  dst[((size_t)(t * 8 + (i >> 5)) * NOCP + (o + ocoff)) * 32 + (i & 31)] =
      __float2bfloat16(src[idx]);
}

__global__ void locations_k(float* __restrict__ out, int HW, int W, float s) {
  int i = blockIdx.x * 256 + threadIdx.x;
  if (i >= HW) return;
  int y = i / W, x = i - y * W;
  out[2 * i + 0] = x * s + 0.5f * s;
  out[2 * i + 1] = y * s + 0.5f * s;
}

// Implicit-GEMM conv3x3 via MFMA 16x16x32 bf16.
// Block: 256 thr = 4 waves (2M x 2N). Tile: 128 pixels (8 rows x 16 cols) x NOC ocs.
// blockIdx.y selects the oc-half (ocbase = y*NOC) so NREP=4 towers run 2 blocks/tile:
// smaller acc tile -> ~168 VGPR -> 3 waves/SIMD (12 waves/CU) for latency hiding.
// K-loop: 8 ic-chunks x 9 taps, K=32 per step. s_in: [10][18][40] bf16.
// Weights: direct global->VGPR, double-buffered one tap ahead (L2-resident),
// tap loop barrier-free (r1 structure — LDS-staged weight variants measured 2x slower).
// GN finalize fused: NORM_IN blocks compute per-channel a/c from statsIn.
// OUT_MODE: 0 = NHWC bf16 dst; 1 = d_out fp32 (logits oc<80, ctr oc==80 -> ch84);
//           2 = d_out fp32 expf(scale*v) at ch 80+oc.
template <int NREP, bool NORM_IN, bool STATS, int OUT_MODE, bool SRC_NCHW>
__global__ __launch_bounds__(256, 3) void conv_mfma_k(
    const void* __restrict__ srcv, const __hip_bfloat16* __restrict__ wpk,
    const float* __restrict__ bias, const float* __restrict__ bias2,
    const float* __restrict__ statsIn, const float* __restrict__ gamma,
    const float* __restrict__ beta, float inv_cnt,
    __hip_bfloat16* __restrict__ dst, float* __restrict__ out,
    float* __restrict__ statsOut, const float* __restrict__ scales, int lvl,
    int H, int W, int oc_valid, int nTx, int NOCP) {
  constexpr int NOC = NREP * 32;
  __shared__ __align__(16) short s_in[180 * 40];
  __shared__ float s_red[64];
  __shared__ float s_a[256], s_c[256];

  const int tid = threadIdx.x;
  const int lane = tid & 63;
  const int wave = tid >> 6;
  const int wm = wave >> 1;  // 0..1
  const int wn = wave & 1;   // 0..1
  const int tIdx = blockIdx.x;
  const int ty = tIdx / nTx, tx = tIdx - ty * nTx;
  const int x0 = tx * 16, y0 = ty * 8;
  const int b = blockIdx.z;
  const int ocbase = blockIdx.y * NOC;
  const int HW = H * W;
  const int l15 = lane & 15;
  const int kg = lane >> 4;  // 0..3
  const int q8 = (tid & 3) * 8;

  if (STATS && tid < 64) s_red[tid] = 0.f;
  if (NORM_IN) {
    // fused GN finalize: stats slot -> per-channel scale/shift in LDS
    int g = tid >> 3;
    float s = statsIn[(b * 32 + g) * 2 + 0];
    float ss = statsIn[(b * 32 + g) * 2 + 1];
    float m = s * inv_cnt;
    float var = fmaf(-m, m, ss * inv_cnt);
    float rs = rsqrtf(var + 1e-5f);
    float avv = rs * gamma[tid];
    s_a[tid] = avv;
    s_c[tid] = fmaf(-m, avv, beta[tid]);
  }

  f32x4 acc[4][NREP];
#pragma unroll
  for (int m = 0; m < 4; ++m)
#pragma unroll
    for (int n = 0; n < NREP; ++n) acc[m][n] = (f32x4){0.f, 0.f, 0.f, 0.f};

  // per-lane weight pointer: elem = ((tap*8+chunk)*NOCP + ocbase + oc_l)*32 + kg*8
  const short* wlane =
      (const short*)wpk + ((ocbase + wn * NREP * 16 + l15) * 32 + kg * 8);
  const size_t TAPSTR = (size_t)8 * NOCP * 32;

  for (int chunk = 0; chunk < 8; ++chunk) {
    const int ic0 = chunk * 32;
    __syncthreads();  // protect s_in from previous chunk's readers (also orders s_a/s_c)
    if (SRC_NCHW) {
      // one pixel per thread (180 active), 32 coalesced ic loads, 4 ds_write_b128
      const float* srcf = (const float*)srcv;
      const int pix = tid;
      if (pix < 180) {
        int prow = pix / 18;
        int pcol = pix - prow * 18;
        int gy = y0 + prow - 1, gx = x0 + pcol - 1;
        short8 sv[4];
        bool valid = (gy >= 0 && gy < H && gx >= 0 && gx < W);
        if (valid) {
          const float* p = srcf + (((size_t)(b * 256 + ic0)) * H + gy) * W + gx;
#pragma unroll
          for (int q = 0; q < 4; ++q)
#pragma unroll
            for (int j = 0; j < 8; ++j)
              sv[q][j] = f2bfbits(p[(size_t)(q * 8 + j) * HW]);
        } else {
#pragma unroll
          for (int q = 0; q < 4; ++q) sv[q] = (short8)0;
        }
#pragma unroll
        for (int q = 0; q < 4; ++q) *(short8*)(s_in + pix * 40 + q * 8) = sv[q];
      }
    } else {
      const __hip_bfloat16* srcb = (const __hip_bfloat16*)srcv;
      float av[8], cv[8];
#pragma unroll
      for (int j = 0; j < 8; ++j) {
        int c2 = ic0 + q8 + j;
        av[j] = s_a[c2];
        cv[j] = s_c[c2];
      }
      for (int idx = tid; idx < 720; idx += 256) {  // 180 pix x 4 quads(8ic)
        int pix = idx >> 2;
        int prow = pix / 18;
        int pcol = pix - prow * 18;
        int gy = y0 + prow - 1, gx = x0 + pcol - 1;
        short8 o8 = (short8)0;
        if (gy >= 0 && gy < H && gx >= 0 && gx < W) {
          const short* sp =
              (const short*)srcb + ((((size_t)b * H + gy) * W + gx) * 256 + ic0 + q8);
          short8 v8 = *(const short8*)sp;
#pragma unroll
          for (int j = 0; j < 8; ++j)
            o8[j] = f2bfbits(fmaxf(fmaf(bfbits2f(v8[j]), av[j], cv[j]), 0.f));
        }
        *(short8*)(s_in + pix * 40 + q8) = o8;
      }
    }
    __syncthreads();

    const short* wch = wlane + (size_t)chunk * NOCP * 32;
    short8 bwA[NREP], bwB[NREP];
#pragma unroll
    for (int n = 0; n < NREP; ++n) bwA[n] = *(const short8*)(wch + n * 512);

    auto tapbody = [&](int tap, short8* curw, short8* nxtw) {
      if (tap < 8) {  // prefetch next tap's weights (L2-resident)
        const short* wt = wch + (size_t)(tap + 1) * TAPSTR;
#pragma unroll
        for (int n = 0; n < NREP; ++n) nxtw[n] = *(const short8*)(wt + n * 512);
      }
      const int dy = tap / 3, dx = tap - dy * 3;
      short8 af[4];
#pragma unroll
      for (int m = 0; m < 4; ++m)
        af[m] = *(const short8*)(s_in + ((wm * 4 + m + dy) * 18 + (l15 + dx)) * 40 + kg * 8);
#pragma unroll
      for (int m = 0; m < 4; ++m)
#pragma unroll
        for (int n = 0; n < NREP; ++n)
          acc[m][n] = __builtin_amdgcn_mfma_f32_16x16x32_bf16(af[m], curw[n], acc[m][n], 0, 0, 0);
    };
#pragma unroll
    for (int tap = 0; tap < 9; tap += 2) {
      tapbody(tap, bwA, bwB);
      if (tap + 1 < 9) tapbody(tap + 1, bwB, bwA);
    }
  }

  // epilogue: bias, store, GN stats
  const int masks[5] = {1, 2, 4, 16, 32};
#pragma unroll
  for (int n = 0; n < NREP; ++n) {
    int oc_l = wn * NREP * 16 + n * 16 + l15;
    int oc_g = ocbase + oc_l;
    float bv;
    if (OUT_MODE == 1)
      bv = (oc_g < 80) ? bias[oc_g] : ((oc_g == 80) ? bias2[0] : 0.f);
    else
      bv = (oc_g < oc_valid) ? bias[oc_g] : 0.f;
    float lsum = 0.f, lssq = 0.f;
#pragma unroll
    for (int m = 0; m < 4; ++m) {
      int oy = y0 + wm * 4 + m;
#pragma unroll
      for (int r = 0; r < 4; ++r) {
        int ox = x0 + kg * 4 + r;
        bool valid = (oy < H) && (ox < W) && (oc_g < oc_valid);
        float v = acc[m][n][r] + bv;
        if (valid) {
          if (OUT_MODE == 0) {
            dst[(((size_t)b * H + oy) * W + ox) * 256 + oc_g] = __float2bfloat16(v);
          } else if (OUT_MODE == 1) {
            int och = (oc_g == 80) ? 84 : oc_g;
            out[(size_t)b * TOT85 + (size_t)och * HW + oy * W + ox] = v;
          } else {
            out[(size_t)b * TOT85 + (size_t)(80 + oc_g) * HW + oy * W + ox] =
                expf(scales[lvl] * v);
          }
          if (STATS) {
            lsum += v;
            lssq += v * v;
          }
        }
      }
    }
    if (STATS) {
#pragma unroll
      for (int s = 0; s < 5; ++s) {
        lsum += __shfl_xor(lsum, masks[s], 64);
        lssq += __shfl_xor(lssq, masks[s], 64);
      }
      if ((lane & 55) == 0) {  // lanes 0 and 8
        int g2 = ((wn * NREP + n) * 2 + ((lane >> 3) & 1)) * 2;
        atomicAdd(&s_red[g2 + 0], lsum);
        atomicAdd(&s_red[g2 + 1], lssq);
      }
    }
  }
  if (STATS) {
    __syncthreads();
    // this block covers NREP*32 ocs = NREP*4 groups = NREP*8 stats floats
    if (tid < NREP * 8)
      atomicAdd(&statsOut[(size_t)b * 64 + (ocbase >> 2) + tid], s_red[tid]);
  }
}

extern "C" void kernel_launch(void* const* d_in, const int* in_sizes, int n_in,
                              void* d_out_v, int out_size, void* d_ws, size_t ws_size,
                              hipStream_t stream) {
  (void)in_sizes; (void)n_in; (void)out_size; (void)ws_size;
  static const int HS[5] = {100, 50, 25, 13, 7};
  static const int WSd[5] = {152, 76, 38, 19, 10};
  static const int STRD[5] = {8, 16, 32, 64, 128};

  const float* feat[5];
  for (int i = 0; i < 5; ++i) feat[i] = (const float*)d_in[i];
  const float* cls_w = (const float*)d_in[5];
  const float* cls_b = (const float*)d_in[6];
  const float* cls_g = (const float*)d_in[7];
  const float* cls_bb = (const float*)d_in[8];
  const float* box_w = (const float*)d_in[9];
  const float* box_b = (const float*)d_in[10];
  const float* box_g = (const float*)d_in[11];
  const float* box_bb = (const float*)d_in[12];
  const float* logits_w = (const float*)d_in[13];
  const float* logits_b = (const float*)d_in[14];
  const float* ctr_w = (const float*)d_in[15];
  const float* ctr_b = (const float*)d_in[16];
  const float* reg_w = (const float*)d_in[17];
  const float* reg_b = (const float*)d_in[18];
  const float* scales = (const float*)d_in[19];
  float* d_out = (float*)d_out_v;

  char* wsp = (char*)d_ws;
  size_t off = 0;
  auto carve = [&](size_t bytes) -> char* {
    char* p = wsp + off;
    off += (bytes + 255) & ~(size_t)255;
    return p;
  };
  const size_t MAXE = (size_t)8 * 100 * 152 * 256;  // 31.13M elems
  __hip_bfloat16* bufA = (__hip_bfloat16*)carve(MAXE * 2);
  __hip_bfloat16* bufB = (__hip_bfloat16*)carve(MAXE * 2);
  const size_t TW = (size_t)9 * 8 * 256 * 32;  // 589824 elems per tower conv
  __hip_bfloat16* wpk_cls = (__hip_bfloat16*)carve(4 * TW * 2);
  __hip_bfloat16* wpk_box = (__hip_bfloat16*)carve(4 * TW * 2);
  __hip_bfloat16* wpk_clsh = (__hip_bfloat16*)carve((size_t)9 * 8 * 96 * 32 * 2);
  __hip_bfloat16* wpk_regh = (__hip_bfloat16*)carve((size_t)9 * 8 * 32 * 32 * 2);
  // 40 stats slots (5 lvl x 2 towers x 4 convs), 8*64 floats each; one memset/launch
  float* stats_all = (float*)carve((size_t)40 * 8 * 64 * 4);

  hipMemsetAsync(stats_all, 0, (size_t)40 * 8 * 64 * 4, stream);

  auto rp = [&](const float* s, __hip_bfloat16* d, int O, int NOCP, int ocoff) {
    int total = O * 2304;
    hipLaunchKernelGGL(repack_k, dim3((total + 255) / 256), dim3(256), 0, stream, s, d, O, NOCP,
                       ocoff);
  };
  for (int i = 0; i < 4; ++i) {
    rp(cls_w + (size_t)i * 256 * 2304, wpk_cls + (size_t)i * TW, 256, 256, 0);
    rp(box_w + (size_t)i * 256 * 2304, wpk_box + (size_t)i * TW, 256, 256, 0);
  }
  rp(logits_w, wpk_clsh, 80, 96, 0);
  rp(ctr_w, wpk_clsh, 1, 96, 80);
  rp(reg_w, wpk_regh, 4, 32, 0);

  size_t out_lvl_off = 0, loc_off = 0;
  const size_t OUT0 = (size_t)8 * TOT85;

  for (int l = 0; l < 5; ++l) {
    int H = HS[l], W = WSd[l], HW = H * W;
    int nTx = (W + 15) / 16, nTy = (H + 7) / 8;
    dim3 gridT(nTx * nTy, 2, 8);  // towers: y = oc-half
    dim3 gridH(nTx * nTy, 1, 8);  // heads
    dim3 blk(256);
    float inv_cnt = 1.f / (8.f * (float)HW);
    float* out_lvl = d_out + out_lvl_off;

    hipLaunchKernelGGL(locations_k, dim3((HW + 255) / 256), blk, 0, stream,
                       d_out + OUT0 + 2 * loc_off, HW, W, (float)STRD[l]);

    for (int t = 0; t < 2; ++t) {
      const __hip_bfloat16* wpkT = (t == 0) ? wpk_cls : wpk_box;
      const float* bt = (t == 0) ? cls_b : box_b;
      const float* gt = (t == 0) ? cls_g : box_g;
      const float* bbt = (t == 0) ? cls_bb : box_bb;
      float* slot = stats_all + (size_t)(l * 2 + t) * 4 * 512;  // 512 floats per conv slot

      // conv 0: NCHW f32 input, no norm, writes stats slot 0
      hipLaunchKernelGGL((conv_mfma_k<4, false, true, 0, true>), gridT, blk, 0, stream,
                         (const void*)feat[l], wpkT, bt, (const float*)nullptr,
                         (const float*)nullptr, (const float*)nullptr, (const float*)nullptr,
                         0.f, bufA, (float*)nullptr, slot, scales, l, H, W, 256, nTx, 256);
      __hip_bfloat16* cur = bufA;
      __hip_bfloat16* nxt = bufB;
      for (int i = 1; i < 4; ++i) {
        hipLaunchKernelGGL((conv_mfma_k<4, true, true, 0, false>), gridT, blk, 0, stream,
                           (const void*)cur, wpkT + (size_t)i * TW, bt + i * 256,
                           (const float*)nullptr, slot + (size_t)(i - 1) * 512,
                           gt + (i - 1) * 256, bbt + (i - 1) * 256, inv_cnt, nxt,
                           (float*)nullptr, slot + (size_t)i * 512, scales, l, H, W, 256, nTx,
                           256);
        __hip_bfloat16* tmp = cur;
        cur = nxt;
        nxt = tmp;
      }
      if (t == 0) {
        hipLaunchKernelGGL((conv_mfma_k<3, true, false, 1, false>), gridH, blk, 0, stream,
                           (const void*)cur, wpk_clsh, logits_b, ctr_b,
                           slot + (size_t)3 * 512, gt + 3 * 256, bbt + 3 * 256, inv_cnt,
                           (__hip_bfloat16*)nullptr, out_lvl, (float*)nullptr, scales, l, H, W,
                           81, nTx, 96);
      } else {
        hipLaunchKernelGGL((conv_mfma_k<1, true, false, 2, false>), gridH, blk, 0, stream,
                           (const void*)cur, wpk_regh, reg_b, (const float*)nullptr,
                           slot + (size_t)3 * 512, gt + 3 * 256, bbt + 3 * 256, inv_cnt,
                           (__hip_bfloat16*)nullptr, out_lvl, (float*)nullptr, scales, l, H, W,
                           4, nTx, 32);
      }
    }
    out_lvl_off += (size_t)85 * HW;
    loc_off += HW;
  }
}